// Round 6
// baseline (686.846 us; speedup 1.0000x reference)
//
#include <hip/hip_runtime.h>

#define N_NODES 50000
#define N_EDGES 800000
#define FDIM 128
#define NROWS 100000   // B * N_NODES
#define BN_EPS 1e-5f
#define SCAN_BLOCKS 196   // ceil(50000 / 256)
#define AGG_BLOCKS 12500  // 4 nodes per block
#define RED_BLOCKS 50

typedef unsigned short ushort_t;
typedef unsigned int uint_t;
typedef __attribute__((ext_vector_type(8))) short bf16x8;           // MFMA A/B frag
typedef __attribute__((ext_vector_type(4))) float f32x4;            // MFMA C/D frag
typedef __attribute__((ext_vector_type(8))) unsigned short u16x8;   // 16B gather unit

// round-to-nearest-even fp32 -> bf16
__device__ inline ushort_t f2bf(float f) {
    uint_t x = __float_as_uint(f);
    x += 0x7fffu + ((x >> 16) & 1u);
    return (ushort_t)(x >> 16);
}
__device__ inline float bf2f(ushort_t u) {
    return __uint_as_float((uint_t)u << 16);
}
// split-bf16: f = hi + lo with |err| ~ 2^-18 |f|
__device__ inline void split4(float4 v, bf16x8& hi, bf16x8& lo, int base) {
    float f[4] = {v.x, v.y, v.z, v.w};
    #pragma unroll
    for (int t = 0; t < 4; ++t) {
        ushort_t h = f2bf(f[t]);
        float fh = __uint_as_float((uint_t)h << 16);
        ushort_t l = f2bf(f[t] - fh);
        hi[base + t] = (short)h;
        lo[base + t] = (short)l;
    }
}

// ---------------- CSR build (per-destination buckets) ----------------

__global__ __launch_bounds__(256) void hist_kernel(const int* __restrict__ col,
                                                   int* __restrict__ cnt) {
    int e = blockIdx.x * 256 + threadIdx.x;
    if (e < N_EDGES) atomicAdd(&cnt[col[e]], 1);
}

__global__ __launch_bounds__(256) void scan_partials_sum(const int* __restrict__ cnt,
                                                         int* __restrict__ partials) {
    __shared__ int ws[4];
    int tid = threadIdx.x, lane = tid & 63, wid = tid >> 6;
    int i = blockIdx.x * 256 + tid;
    int v = (i < N_NODES) ? cnt[i] : 0;
    #pragma unroll
    for (int d = 32; d > 0; d >>= 1) v += __shfl_xor(v, d);
    if (lane == 0) ws[wid] = v;
    __syncthreads();
    if (tid == 0) partials[blockIdx.x] = ws[0] + ws[1] + ws[2] + ws[3];
}

__global__ __launch_bounds__(256) void scan_partials_scan(int* __restrict__ partials,
                                                          int* __restrict__ offsets) {
    __shared__ int ws[4];
    int tid = threadIdx.x, lane = tid & 63, wid = tid >> 6;
    int v = (tid < SCAN_BLOCKS) ? partials[tid] : 0;
    int x = v;
    #pragma unroll
    for (int d = 1; d < 64; d <<= 1) {
        int y = __shfl_up(x, d);
        if (lane >= d) x += y;
    }
    if (lane == 63) ws[wid] = x;
    __syncthreads();
    int woff = 0;
    for (int w = 0; w < wid; ++w) woff += ws[w];
    if (tid < SCAN_BLOCKS) partials[tid] = woff + x - v;   // exclusive
    if (tid == 255) offsets[N_NODES] = woff + x;           // grand total
}

__global__ __launch_bounds__(256) void scan_final(const int* __restrict__ cnt,
                                                  const int* __restrict__ partials,
                                                  int* __restrict__ offsets,
                                                  int* __restrict__ cursor) {
    __shared__ int ws[4];
    int tid = threadIdx.x, lane = tid & 63, wid = tid >> 6;
    int i = blockIdx.x * 256 + tid;
    int v = (i < N_NODES) ? cnt[i] : 0;
    int x = v;
    #pragma unroll
    for (int d = 1; d < 64; d <<= 1) {
        int y = __shfl_up(x, d);
        if (lane >= d) x += y;
    }
    if (lane == 63) ws[wid] = x;
    __syncthreads();
    int woff = 0;
    for (int w = 0; w < wid; ++w) woff += ws[w];
    if (i < N_NODES) {
        int off = partials[blockIdx.x] + woff + x - v;
        offsets[i] = off;
        cursor[i] = off;
    }
}

__global__ __launch_bounds__(256) void bucket_kernel(const int* __restrict__ row,
                                                     const int* __restrict__ col,
                                                     int* __restrict__ cursor,
                                                     int* __restrict__ srcbuf) {
    int e = blockIdx.x * 256 + threadIdx.x;
    if (e < N_EDGES) {
        int c = col[e];
        int p = atomicAdd(&cursor[c], 1);
        srcbuf[p] = row[e];
    }
}

// ---------------- W pre-transform: Wt[n][k] split into hi/lo bf16 planes ----------------
__global__ __launch_bounds__(256) void wsplit_kernel(const float* __restrict__ W1,
                                                     const float* __restrict__ W2,
                                                     ushort_t* __restrict__ wt) {
    int idx = blockIdx.x * 256 + threadIdx.x;   // 0..32767
    int which = idx >> 14;
    int e = idx & 16383;                         // e = k*128 + n (coalesced read)
    int k = e >> 7, n = e & 127;
    float f = (which ? W2 : W1)[e];
    ushort_t h = f2bf(f);
    float fh = __uint_as_float((uint_t)h << 16);
    ushort_t l = f2bf(f - fh);
    size_t base = (size_t)which * 32768;
    wt[base + n * 128 + k] = h;                  // hi plane
    wt[base + 16384 + n * 128 + k] = l;          // lo plane
}

// ---------------- GEMM via split-bf16 MFMA ----------------
template <bool BN>
__global__ __launch_bounds__(256) void gemm_mfma(const float* __restrict__ A,
                                                 const ushort_t* __restrict__ wt,
                                                 const float* __restrict__ coef,
                                                 ushort_t* __restrict__ C) {
    __shared__ short lds[32768];  // Ah[0,8192) Al[8192,16384) Wh[16384,24576) Wl[24576,32768)
    int tid = threadIdx.x;
    long r0 = (long)blockIdx.x * 64;
    const float4* A4 = (const float4*)A;
    const float4* coef4 = (const float4*)coef;

    #pragma unroll
    for (int i = 0; i < 4; ++i) {
        int li = tid + i * 256;
        int r = li >> 4, j = li & 15;        // row 0..63, k-block 0..15
        long gr = r0 + r;
        float4 va = make_float4(0.f, 0.f, 0.f, 0.f), vb = va;
        if (gr < NROWS) { va = A4[gr * 32 + j * 2]; vb = A4[gr * 32 + j * 2 + 1]; }
        if (BN) {
            float4 sc = coef4[j * 2], sh = coef4[32 + j * 2];
            va.x = fmaxf(va.x * sc.x + sh.x, 0.f);
            va.y = fmaxf(va.y * sc.y + sh.y, 0.f);
            va.z = fmaxf(va.z * sc.z + sh.z, 0.f);
            va.w = fmaxf(va.w * sc.w + sh.w, 0.f);
            sc = coef4[j * 2 + 1]; sh = coef4[32 + j * 2 + 1];
            vb.x = fmaxf(vb.x * sc.x + sh.x, 0.f);
            vb.y = fmaxf(vb.y * sc.y + sh.y, 0.f);
            vb.z = fmaxf(vb.z * sc.z + sh.z, 0.f);
            vb.w = fmaxf(vb.w * sc.w + sh.w, 0.f);
        }
        bf16x8 vh, vl;
        split4(va, vh, vl, 0);
        split4(vb, vh, vl, 4);
        int off = r * 128 + ((j ^ (r & 15)) * 8);
        *(bf16x8*)&lds[off] = vh;
        *(bf16x8*)&lds[8192 + off] = vl;
    }

    int w = tid >> 6, l = tid & 63;
    int m = l & 15, q = l >> 4;
    for (int half = 0; half < 2; ++half) {
        __syncthreads();
        #pragma unroll
        for (int i = 0; i < 8; ++i) {
            int li = tid + i * 256;
            int p = li >> 10;                 // 0=hi 1=lo
            int rest = li & 1023;
            int nl = rest >> 4, j = rest & 15;
            bf16x8 v = *(const bf16x8*)&wt[(size_t)p * 16384 + (half * 64 + nl) * 128 + j * 8];
            *(bf16x8*)&lds[16384 + p * 8192 + nl * 128 + ((j ^ (nl & 15)) * 8)] = v;
        }
        __syncthreads();

        f32x4 acc[4] = {};
        #pragma unroll
        for (int s = 0; s < 4; ++s) {
            int x = (s * 4 + q) ^ m;
            int aoff = (w * 16 + m) * 128 + x * 8;
            bf16x8 ah = *(const bf16x8*)&lds[aoff];
            bf16x8 al = *(const bf16x8*)&lds[8192 + aoff];
            #pragma unroll
            for (int c = 0; c < 4; ++c) {
                int boff = 16384 + (c * 16 + m) * 128 + x * 8;
                bf16x8 bh = *(const bf16x8*)&lds[boff];
                bf16x8 bl = *(const bf16x8*)&lds[8192 + boff];
                acc[c] = __builtin_amdgcn_mfma_f32_16x16x32_bf16(al, bh, acc[c], 0, 0, 0);
                acc[c] = __builtin_amdgcn_mfma_f32_16x16x32_bf16(ah, bl, acc[c], 0, 0, 0);
                acc[c] = __builtin_amdgcn_mfma_f32_16x16x32_bf16(ah, bh, acc[c], 0, 0, 0);
            }
        }

        #pragma unroll
        for (int c = 0; c < 4; ++c) {
            #pragma unroll
            for (int r = 0; r < 4; ++r) {
                long gr = r0 + w * 16 + q * 4 + r;
                if (gr < NROWS)
                    C[gr * 128 + half * 64 + c * 16 + m] = f2bf(acc[c][r]);
            }
        }
    }
}

// ---------------- Aggregate + fused BN partial stats ----------------
// Wave per node. Lane = (q, l16): quarter q -> (batch = q&1, phase = q>>1).
// Lane loads ushort8 (16B); 16 lanes cover a 256B bf16 row; one wave-instr
// gathers 4 rows (2 edges x 2 batches). Cross-phase shfl_xor(32) combine.
// Block accumulates per-feature sum/sumsq into LDS (atomic, 2-way same-addr),
// writes 256-float partials for stats_reduce.
__global__ __launch_bounds__(256) void aggregate_bf16(const ushort_t* __restrict__ sup,
                                                      const int* __restrict__ offsets,
                                                      const int* __restrict__ srcbuf,
                                                      float* __restrict__ agg,
                                                      float* __restrict__ spart) {
    __shared__ float s_sum[128], s_sq[128];
    int tid = threadIdx.x;
    int lane = tid & 63, wid = tid >> 6;
    if (tid < 128) { s_sum[tid] = 0.f; s_sq[tid] = 0.f; }
    __syncthreads();
    int node = blockIdx.x * 4 + wid;        // 12500*4 = 50000 exactly
    int q = lane >> 4, l16 = lane & 15;
    int b = q & 1, phase = q >> 1;
    int beg = offsets[node], end = offsets[node + 1];
    const ushort_t* base = sup + (size_t)b * (N_NODES * FDIM) + l16 * 8;
    float acc[8] = {};
    for (int i = beg; i < end; i += 64) {
        int m = end - i; if (m > 64) m = 64;
        int idx = (i + lane < end) ? srcbuf[i + lane] : 0;  // coalesced index load
        int tmax = (m + 1) >> 1;
        #pragma unroll 4
        for (int t = 0; t < tmax; ++t) {
            int j = 2 * t + phase;
            int r = __shfl(idx, j & 63);
            u16x8 u = *(const u16x8*)(base + (size_t)r * FDIM);
            if (j < m) {
                #pragma unroll
                for (int k = 0; k < 8; ++k) acc[k] += bf2f(u[k]);
            }
        }
    }
    // combine phase 0/1 partials (lanes ^32 hold same (batch, cols))
    #pragma unroll
    for (int k = 0; k < 8; ++k) acc[k] += __shfl_xor(acc[k], 32);
    // row write: all 64 lanes, one coalesced float4 store covers both batch rows
    float4 wv = phase ? make_float4(acc[4], acc[5], acc[6], acc[7])
                      : make_float4(acc[0], acc[1], acc[2], acc[3]);
    ((float4*)agg)[(size_t)(b * N_NODES + node) * 32 + l16 * 2 + phase] = wv;
    // stats from phase-0 lanes (each final row counted once)
    if (phase == 0) {
        #pragma unroll
        for (int k = 0; k < 8; ++k) {
            atomicAdd(&s_sum[l16 * 8 + k], acc[k]);
            atomicAdd(&s_sq[l16 * 8 + k], acc[k] * acc[k]);
        }
    }
    __syncthreads();
    if (tid < 128) {
        spart[(size_t)blockIdx.x * 256 + tid] = s_sum[tid];
        spart[(size_t)blockIdx.x * 256 + 128 + tid] = s_sq[tid];
    }
}

__global__ __launch_bounds__(256) void stats_reduce(const float* __restrict__ spart,
                                                    float* __restrict__ stats) {
    int tid = threadIdx.x;
    float s = 0.f;
    for (int p = blockIdx.x; p < AGG_BLOCKS; p += RED_BLOCKS)
        s += spart[(size_t)p * 256 + tid];
    atomicAdd(&stats[tid], s);
}

__global__ void bn_coef_kernel(const float* __restrict__ stats,
                               const float* __restrict__ gamma,
                               const float* __restrict__ beta,
                               float* __restrict__ coef) {
    int f = threadIdx.x;
    if (f < 128) {
        float inv = 1.0f / (float)NROWS;
        float mean = stats[f] * inv;
        float var = stats[128 + f] * inv - mean * mean;  // biased var, matches jnp.var
        float scale = gamma[f] / sqrtf(var + BN_EPS);
        coef[f] = scale;
        coef[128 + f] = beta[f] - mean * scale;
    }
}

// ---------------- Layer 3: fused BN+ReLU GEMV + CSR gather ----------------

__global__ __launch_bounds__(256) void gemv_bn_kernel(const float* __restrict__ h,
                                                      const float* __restrict__ coef,
                                                      const float* __restrict__ W3,
                                                      float* __restrict__ sup3) {
    int lane = threadIdx.x & 63, wid = threadIdx.x >> 6;
    int gw = blockIdx.x * 4 + wid;
    if (gw >= NROWS) return;
    float2 w  = ((const float2*)W3)[lane];
    float2 sc = ((const float2*)coef)[lane];
    float2 sh = ((const float2*)(coef + 128))[lane];
    float2 v  = ((const float2*)h)[(size_t)gw * 64 + lane];
    v.x = fmaxf(v.x * sc.x + sh.x, 0.f);
    v.y = fmaxf(v.y * sc.y + sh.y, 0.f);
    float s = v.x * w.x + v.y * w.y;
    #pragma unroll
    for (int d = 32; d > 0; d >>= 1) s += __shfl_xor(s, d);
    if (lane == 0) sup3[gw] = s;
}

// out[b,n] = b3 + sum over CSR in-edges of sup3[b, src].
__global__ __launch_bounds__(256) void gather_out_kernel(const int* __restrict__ offsets,
                                                         const int* __restrict__ srcbuf,
                                                         const float* __restrict__ sup3,
                                                         const float* __restrict__ b3,
                                                         float* __restrict__ out) {
    int n = blockIdx.x * 256 + threadIdx.x;
    if (n >= N_NODES) return;
    int beg = offsets[n], end = offsets[n + 1];
    float s0 = 0.f, s1 = 0.f;
    for (int i = beg; i < end; ++i) {
        int r = srcbuf[i];
        s0 += sup3[r];
        s1 += sup3[N_NODES + r];
    }
    float b = b3[0];
    out[n] = s0 + b;
    out[N_NODES + n] = s1 + b;
}

// ---------------- launch ----------------

extern "C" void kernel_launch(void* const* d_in, const int* in_sizes, int n_in,
                              void* d_out, int out_size, void* d_ws, size_t ws_size,
                              hipStream_t stream) {
    const float* x      = (const float*)d_in[0];
    const int*   ei     = (const int*)d_in[1];
    const float* W1     = (const float*)d_in[2];
    // d_in[3] = b1: per-feature bias before BN cancels exactly (shifts mean identically)
    const float* W2     = (const float*)d_in[4];
    // d_in[5] = b2: same cancellation
    const float* W3     = (const float*)d_in[6];
    const float* b3     = (const float*)d_in[7];
    const float* gamma1 = (const float*)d_in[8];
    const float* beta1  = (const float*)d_in[9];
    const float* gamma2 = (const float*)d_in[10];
    const float* beta2  = (const float*)d_in[11];
    const int* rowp = ei;             // edge_index[0]
    const int* colp = ei + N_EDGES;   // edge_index[1]

    ushort_t* sup   = (ushort_t*)d_ws;              // 12.8M bf16 (25.6 MB)
    float* agg      = (float*)(sup + 12800000);     // 12.8M floats (51.2 MB)
    float* sup3     = agg + 12800000;               // 100k floats
    ushort_t* wt    = (ushort_t*)(sup3 + 100000);   // 65536 ushorts: W1/W2 split planes
    float* stats    = (float*)(wt + 65536);         // 512 floats
    float* coef     = stats + 512;                  // 512 floats
    int*   cnt      = (int*)(coef + 512);           // 50000
    int*   offsets  = cnt + N_NODES;                // 50001
    int*   cursor   = offsets + N_NODES + 1;        // 50000
    int*   srcbuf   = cursor + N_NODES;             // 800000
    int*   scanp    = srcbuf + N_EDGES;             // 196
    float* spart    = (float*)(scanp + 256);        // 12500*256 floats (12.8 MB)
    float* out      = (float*)d_out;

    hipMemsetAsync(cnt, 0, N_NODES * sizeof(int), stream);
    hipMemsetAsync(stats, 0, 512 * sizeof(float), stream);

    // W split/transpose (once per launch) + CSR build
    wsplit_kernel     <<<128,         256, 0, stream>>>(W1, W2, wt);
    hist_kernel       <<<3125,        256, 0, stream>>>(colp, cnt);
    scan_partials_sum <<<SCAN_BLOCKS, 256, 0, stream>>>(cnt, scanp);
    scan_partials_scan<<<1,           256, 0, stream>>>(scanp, offsets);
    scan_final        <<<SCAN_BLOCKS, 256, 0, stream>>>(cnt, scanp, offsets, cursor);
    bucket_kernel     <<<3125,        256, 0, stream>>>(rowp, colp, cursor, srcbuf);

    // layer 1: sup = x@W1 (split-bf16 MFMA), agg = A·sup + fused stats
    gemm_mfma<false><<<1563,       256, 0, stream>>>(x, wt, nullptr, sup);
    aggregate_bf16  <<<AGG_BLOCKS, 256, 0, stream>>>(sup, offsets, srcbuf, agg, spart);
    stats_reduce    <<<RED_BLOCKS, 256, 0, stream>>>(spart, stats);
    bn_coef_kernel  <<<1,          128, 0, stream>>>(stats, gamma1, beta1, coef);

    // layer 2: sup = relu(bn(agg))@W2 (BN fused into staging), agg = A·sup + stats
    gemm_mfma<true> <<<1563,       256, 0, stream>>>(agg, wt + 32768, coef, sup);
    aggregate_bf16  <<<AGG_BLOCKS, 256, 0, stream>>>(sup, offsets, srcbuf, agg, spart);
    stats_reduce    <<<RED_BLOCKS, 256, 0, stream>>>(spart, stats + 256);
    bn_coef_kernel  <<<1,          128, 0, stream>>>(stats + 256, gamma2, beta2, coef + 256);

    // layer 3: sup3 = relu(bn(agg))@W3 (fused GEMV), out = A·sup3 + b3 (CSR gather)
    gemv_bn_kernel   <<<25000, 256, 0, stream>>>(agg, coef + 256, W3, sup3);
    gather_out_kernel<<<SCAN_BLOCKS, 256, 0, stream>>>(offsets, srcbuf, sup3, b3, out);
}

// Round 7
// 517.361 us; speedup vs baseline: 1.3276x; 1.3276x over previous
//
#include <hip/hip_runtime.h>

#define N_NODES 50000
#define N_EDGES 800000
#define FDIM 128
#define NROWS 100000   // B * N_NODES
#define BN_EPS 1e-5f
#define SCAN_BLOCKS 196   // ceil(50000 / 256)
#define AGG_BLOCKS 12500  // 4 nodes per block
#define RED_BLOCKS 50

typedef unsigned short ushort_t;
typedef unsigned int uint_t;
typedef __attribute__((ext_vector_type(8))) short bf16x8;   // MFMA A/B frag
typedef __attribute__((ext_vector_type(4))) float f32x4;    // MFMA C/D frag

// round-to-nearest-even fp32 -> bf16
__device__ inline ushort_t f2bf(float f) {
    uint_t x = __float_as_uint(f);
    x += 0x7fffu + ((x >> 16) & 1u);
    return (ushort_t)(x >> 16);
}
__device__ inline float4 bf4_to_f4(ushort4 u) {
    float4 f;
    f.x = __uint_as_float((uint_t)u.x << 16);
    f.y = __uint_as_float((uint_t)u.y << 16);
    f.z = __uint_as_float((uint_t)u.z << 16);
    f.w = __uint_as_float((uint_t)u.w << 16);
    return f;
}
// split-bf16: f = hi + lo with |err| ~ 2^-18 |f|
__device__ inline void split4(float4 v, bf16x8& hi, bf16x8& lo, int base) {
    float f[4] = {v.x, v.y, v.z, v.w};
    #pragma unroll
    for (int t = 0; t < 4; ++t) {
        ushort_t h = f2bf(f[t]);
        float fh = __uint_as_float((uint_t)h << 16);
        ushort_t l = f2bf(f[t] - fh);
        hi[base + t] = (short)h;
        lo[base + t] = (short)l;
    }
}

// ---------------- CSR build (per-destination buckets) ----------------

__global__ __launch_bounds__(256) void hist_kernel(const int* __restrict__ col,
                                                   int* __restrict__ cnt) {
    int e = blockIdx.x * 256 + threadIdx.x;
    if (e < N_EDGES) atomicAdd(&cnt[col[e]], 1);
}

__global__ __launch_bounds__(256) void scan_partials_sum(const int* __restrict__ cnt,
                                                         int* __restrict__ partials) {
    __shared__ int ws[4];
    int tid = threadIdx.x, lane = tid & 63, wid = tid >> 6;
    int i = blockIdx.x * 256 + tid;
    int v = (i < N_NODES) ? cnt[i] : 0;
    #pragma unroll
    for (int d = 32; d > 0; d >>= 1) v += __shfl_xor(v, d);
    if (lane == 0) ws[wid] = v;
    __syncthreads();
    if (tid == 0) partials[blockIdx.x] = ws[0] + ws[1] + ws[2] + ws[3];
}

__global__ __launch_bounds__(256) void scan_partials_scan(int* __restrict__ partials,
                                                          int* __restrict__ offsets) {
    __shared__ int ws[4];
    int tid = threadIdx.x, lane = tid & 63, wid = tid >> 6;
    int v = (tid < SCAN_BLOCKS) ? partials[tid] : 0;
    int x = v;
    #pragma unroll
    for (int d = 1; d < 64; d <<= 1) {
        int y = __shfl_up(x, d);
        if (lane >= d) x += y;
    }
    if (lane == 63) ws[wid] = x;
    __syncthreads();
    int woff = 0;
    for (int w = 0; w < wid; ++w) woff += ws[w];
    if (tid < SCAN_BLOCKS) partials[tid] = woff + x - v;   // exclusive
    if (tid == 255) offsets[N_NODES] = woff + x;           // grand total
}

__global__ __launch_bounds__(256) void scan_final(const int* __restrict__ cnt,
                                                  const int* __restrict__ partials,
                                                  int* __restrict__ offsets,
                                                  int* __restrict__ cursor) {
    __shared__ int ws[4];
    int tid = threadIdx.x, lane = tid & 63, wid = tid >> 6;
    int i = blockIdx.x * 256 + tid;
    int v = (i < N_NODES) ? cnt[i] : 0;
    int x = v;
    #pragma unroll
    for (int d = 1; d < 64; d <<= 1) {
        int y = __shfl_up(x, d);
        if (lane >= d) x += y;
    }
    if (lane == 63) ws[wid] = x;
    __syncthreads();
    int woff = 0;
    for (int w = 0; w < wid; ++w) woff += ws[w];
    if (i < N_NODES) {
        int off = partials[blockIdx.x] + woff + x - v;
        offsets[i] = off;
        cursor[i] = off;
    }
}

__global__ __launch_bounds__(256) void bucket_kernel(const int* __restrict__ row,
                                                     const int* __restrict__ col,
                                                     int* __restrict__ cursor,
                                                     int* __restrict__ srcbuf) {
    int e = blockIdx.x * 256 + threadIdx.x;
    if (e < N_EDGES) {
        int c = col[e];
        int p = atomicAdd(&cursor[c], 1);
        srcbuf[p] = row[e];
    }
}

// ---------------- W pre-transform: Wt[n][k] split into hi/lo bf16 planes ----------------
__global__ __launch_bounds__(256) void wsplit_kernel(const float* __restrict__ W1,
                                                     const float* __restrict__ W2,
                                                     ushort_t* __restrict__ wt) {
    int idx = blockIdx.x * 256 + threadIdx.x;   // 0..32767
    int which = idx >> 14;
    int e = idx & 16383;                         // e = k*128 + n (coalesced read)
    int k = e >> 7, n = e & 127;
    float f = (which ? W2 : W1)[e];
    ushort_t h = f2bf(f);
    float fh = __uint_as_float((uint_t)h << 16);
    ushort_t l = f2bf(f - fh);
    size_t base = (size_t)which * 32768;
    wt[base + n * 128 + k] = h;                  // hi plane
    wt[base + 16384 + n * 128 + k] = l;          // lo plane
}

// ---------------- GEMM via split-bf16 MFMA ----------------
template <bool BN>
__global__ __launch_bounds__(256) void gemm_mfma(const float* __restrict__ A,
                                                 const ushort_t* __restrict__ wt,
                                                 const float* __restrict__ coef,
                                                 ushort_t* __restrict__ C) {
    __shared__ short lds[32768];  // Ah[0,8192) Al[8192,16384) Wh[16384,24576) Wl[24576,32768)
    int tid = threadIdx.x;
    long r0 = (long)blockIdx.x * 64;
    const float4* A4 = (const float4*)A;
    const float4* coef4 = (const float4*)coef;

    #pragma unroll
    for (int i = 0; i < 4; ++i) {
        int li = tid + i * 256;
        int r = li >> 4, j = li & 15;        // row 0..63, k-block 0..15
        long gr = r0 + r;
        float4 va = make_float4(0.f, 0.f, 0.f, 0.f), vb = va;
        if (gr < NROWS) { va = A4[gr * 32 + j * 2]; vb = A4[gr * 32 + j * 2 + 1]; }
        if (BN) {
            float4 sc = coef4[j * 2], sh = coef4[32 + j * 2];
            va.x = fmaxf(va.x * sc.x + sh.x, 0.f);
            va.y = fmaxf(va.y * sc.y + sh.y, 0.f);
            va.z = fmaxf(va.z * sc.z + sh.z, 0.f);
            va.w = fmaxf(va.w * sc.w + sh.w, 0.f);
            sc = coef4[j * 2 + 1]; sh = coef4[32 + j * 2 + 1];
            vb.x = fmaxf(vb.x * sc.x + sh.x, 0.f);
            vb.y = fmaxf(vb.y * sc.y + sh.y, 0.f);
            vb.z = fmaxf(vb.z * sc.z + sh.z, 0.f);
            vb.w = fmaxf(vb.w * sc.w + sh.w, 0.f);
        }
        bf16x8 vh, vl;
        split4(va, vh, vl, 0);
        split4(vb, vh, vl, 4);
        int off = r * 128 + ((j ^ (r & 15)) * 8);
        *(bf16x8*)&lds[off] = vh;
        *(bf16x8*)&lds[8192 + off] = vl;
    }

    int w = tid >> 6, l = tid & 63;
    int m = l & 15, q = l >> 4;
    for (int half = 0; half < 2; ++half) {
        __syncthreads();
        #pragma unroll
        for (int i = 0; i < 8; ++i) {
            int li = tid + i * 256;
            int p = li >> 10;                 // 0=hi 1=lo
            int rest = li & 1023;
            int nl = rest >> 4, j = rest & 15;
            bf16x8 v = *(const bf16x8*)&wt[(size_t)p * 16384 + (half * 64 + nl) * 128 + j * 8];
            *(bf16x8*)&lds[16384 + p * 8192 + nl * 128 + ((j ^ (nl & 15)) * 8)] = v;
        }
        __syncthreads();

        f32x4 acc[4] = {};
        #pragma unroll
        for (int s = 0; s < 4; ++s) {
            int x = (s * 4 + q) ^ m;
            int aoff = (w * 16 + m) * 128 + x * 8;
            bf16x8 ah = *(const bf16x8*)&lds[aoff];
            bf16x8 al = *(const bf16x8*)&lds[8192 + aoff];
            #pragma unroll
            for (int c = 0; c < 4; ++c) {
                int boff = 16384 + (c * 16 + m) * 128 + x * 8;
                bf16x8 bh = *(const bf16x8*)&lds[boff];
                bf16x8 bl = *(const bf16x8*)&lds[8192 + boff];
                acc[c] = __builtin_amdgcn_mfma_f32_16x16x32_bf16(al, bh, acc[c], 0, 0, 0);
                acc[c] = __builtin_amdgcn_mfma_f32_16x16x32_bf16(ah, bl, acc[c], 0, 0, 0);
                acc[c] = __builtin_amdgcn_mfma_f32_16x16x32_bf16(ah, bh, acc[c], 0, 0, 0);
            }
        }

        #pragma unroll
        for (int c = 0; c < 4; ++c) {
            #pragma unroll
            for (int r = 0; r < 4; ++r) {
                long gr = r0 + w * 16 + q * 4 + r;
                if (gr < NROWS)
                    C[gr * 128 + half * 64 + c * 16 + m] = f2bf(acc[c][r]);
            }
        }
    }
}

// ---------------- Aggregate (round-5 hot loop) + atomic-free fused BN stats ----------------
// One wave per node, BOTH batches. Half-wave s handles edges j=2t+s; 32 lanes x ushort4
// cover the 256B bf16 row; 4 loads in flight per wave step. fp32 accumulate.
// Epilogue: s=0 lanes hold final rows of both batches -> per-wave sum/sumsq partials via
// plain ds_write_b128 into sred[4][256], one syncthreads, 256-thread combine -> spart.
__global__ __launch_bounds__(256) void aggregate_bf16(const ushort_t* __restrict__ sup,
                                                      const int* __restrict__ offsets,
                                                      const int* __restrict__ srcbuf,
                                                      float* __restrict__ agg,
                                                      float* __restrict__ spart) {
    __shared__ float sred[4][256];
    int tid = threadIdx.x;
    int lane = tid & 63;
    int wid = tid >> 6;
    int node = blockIdx.x * 4 + wid;        // 12500*4 = 50000 exactly, no stragglers
    int s = lane >> 5;       // half-wave id
    int l32 = lane & 31;
    int beg = offsets[node], end = offsets[node + 1];
    const ushort4* sb0 = (const ushort4*)sup;                               // batch 0
    const ushort4* sb1 = (const ushort4*)(sup + (size_t)N_NODES * FDIM);    // batch 1
    float4 a0 = make_float4(0.f, 0.f, 0.f, 0.f);
    float4 a1 = make_float4(0.f, 0.f, 0.f, 0.f);
    for (int i = beg; i < end; i += 64) {
        int m = end - i; if (m > 64) m = 64;
        int idx = (i + lane < end) ? srcbuf[i + lane] : 0;  // coalesced index load
        int tmax = (m + 1) >> 1;
        #pragma unroll 2
        for (int t = 0; t < tmax; ++t) {
            int j = 2 * t + s;
            int r = __shfl(idx, j & 63);
            ushort4 u0 = sb0[(size_t)r * 32 + l32];
            ushort4 u1 = sb1[(size_t)r * 32 + l32];
            if (j < m) {
                float4 f0 = bf4_to_f4(u0);
                float4 f1 = bf4_to_f4(u1);
                a0.x += f0.x; a0.y += f0.y; a0.z += f0.z; a0.w += f0.w;
                a1.x += f1.x; a1.y += f1.y; a1.z += f1.z; a1.w += f1.w;
            }
        }
    }
    a0.x += __shfl_xor(a0.x, 32); a0.y += __shfl_xor(a0.y, 32);
    a0.z += __shfl_xor(a0.z, 32); a0.w += __shfl_xor(a0.w, 32);
    a1.x += __shfl_xor(a1.x, 32); a1.y += __shfl_xor(a1.y, 32);
    a1.z += __shfl_xor(a1.z, 32); a1.w += __shfl_xor(a1.w, 32);
    float4* ag = (float4*)agg;
    if (s == 0) ag[(size_t)node * 32 + l32] = a0;                       // batch 0 row
    else        ag[(size_t)(N_NODES + node) * 32 + l32] = a1;           // batch 1 row
    // ---- stats epilogue (plain LDS, no atomics) ----
    if (s == 0) {   // lanes 0..31 hold both final rows: cols 4*l32..4*l32+3
        float4 sm, sq;
        sm.x = a0.x + a1.x; sm.y = a0.y + a1.y; sm.z = a0.z + a1.z; sm.w = a0.w + a1.w;
        sq.x = a0.x * a0.x + a1.x * a1.x; sq.y = a0.y * a0.y + a1.y * a1.y;
        sq.z = a0.z * a0.z + a1.z * a1.z; sq.w = a0.w * a0.w + a1.w * a1.w;
        *(float4*)&sred[wid][4 * l32]       = sm;
        *(float4*)&sred[wid][128 + 4 * l32] = sq;
    }
    __syncthreads();
    spart[(size_t)blockIdx.x * 256 + tid] =
        sred[0][tid] + sred[1][tid] + sred[2][tid] + sred[3][tid];
}

__global__ __launch_bounds__(256) void stats_reduce(const float* __restrict__ spart,
                                                    float* __restrict__ stats) {
    int tid = threadIdx.x;
    float s = 0.f;
    for (int p = blockIdx.x; p < AGG_BLOCKS; p += RED_BLOCKS)
        s += spart[(size_t)p * 256 + tid];
    atomicAdd(&stats[tid], s);
}

__global__ void bn_coef_kernel(const float* __restrict__ stats,
                               const float* __restrict__ gamma,
                               const float* __restrict__ beta,
                               float* __restrict__ coef) {
    int f = threadIdx.x;
    if (f < 128) {
        float inv = 1.0f / (float)NROWS;
        float mean = stats[f] * inv;
        float var = stats[128 + f] * inv - mean * mean;  // biased var, matches jnp.var
        float scale = gamma[f] / sqrtf(var + BN_EPS);
        coef[f] = scale;
        coef[128 + f] = beta[f] - mean * scale;
    }
}

// ---------------- Layer 3: fused BN+ReLU GEMV + CSR gather ----------------

__global__ __launch_bounds__(256) void gemv_bn_kernel(const float* __restrict__ h,
                                                      const float* __restrict__ coef,
                                                      const float* __restrict__ W3,
                                                      float* __restrict__ sup3) {
    int lane = threadIdx.x & 63, wid = threadIdx.x >> 6;
    int gw = blockIdx.x * 4 + wid;
    if (gw >= NROWS) return;
    float2 w  = ((const float2*)W3)[lane];
    float2 sc = ((const float2*)coef)[lane];
    float2 sh = ((const float2*)(coef + 128))[lane];
    float2 v  = ((const float2*)h)[(size_t)gw * 64 + lane];
    v.x = fmaxf(v.x * sc.x + sh.x, 0.f);
    v.y = fmaxf(v.y * sc.y + sh.y, 0.f);
    float s = v.x * w.x + v.y * w.y;
    #pragma unroll
    for (int d = 32; d > 0; d >>= 1) s += __shfl_xor(s, d);
    if (lane == 0) sup3[gw] = s;
}

// out[b,n] = b3 + sum over CSR in-edges of sup3[b, src].
__global__ __launch_bounds__(256) void gather_out_kernel(const int* __restrict__ offsets,
                                                         const int* __restrict__ srcbuf,
                                                         const float* __restrict__ sup3,
                                                         const float* __restrict__ b3,
                                                         float* __restrict__ out) {
    int n = blockIdx.x * 256 + threadIdx.x;
    if (n >= N_NODES) return;
    int beg = offsets[n], end = offsets[n + 1];
    float s0 = 0.f, s1 = 0.f;
    for (int i = beg; i < end; ++i) {
        int r = srcbuf[i];
        s0 += sup3[r];
        s1 += sup3[N_NODES + r];
    }
    float b = b3[0];
    out[n] = s0 + b;
    out[N_NODES + n] = s1 + b;
}

// ---------------- launch ----------------

extern "C" void kernel_launch(void* const* d_in, const int* in_sizes, int n_in,
                              void* d_out, int out_size, void* d_ws, size_t ws_size,
                              hipStream_t stream) {
    const float* x      = (const float*)d_in[0];
    const int*   ei     = (const int*)d_in[1];
    const float* W1     = (const float*)d_in[2];
    // d_in[3] = b1: per-feature bias before BN cancels exactly (shifts mean identically)
    const float* W2     = (const float*)d_in[4];
    // d_in[5] = b2: same cancellation
    const float* W3     = (const float*)d_in[6];
    const float* b3     = (const float*)d_in[7];
    const float* gamma1 = (const float*)d_in[8];
    const float* beta1  = (const float*)d_in[9];
    const float* gamma2 = (const float*)d_in[10];
    const float* beta2  = (const float*)d_in[11];
    const int* rowp = ei;             // edge_index[0]
    const int* colp = ei + N_EDGES;   // edge_index[1]

    ushort_t* sup   = (ushort_t*)d_ws;              // 12.8M bf16 (25.6 MB)
    float* agg      = (float*)(sup + 12800000);     // 12.8M floats (51.2 MB)
    float* sup3     = agg + 12800000;               // 100k floats
    ushort_t* wt    = (ushort_t*)(sup3 + 100000);   // 65536 ushorts: W1/W2 split planes
    float* stats    = (float*)(wt + 65536);         // 512 floats
    float* coef     = stats + 512;                  // 512 floats
    int*   cnt      = (int*)(coef + 512);           // 50000
    int*   offsets  = cnt + N_NODES;                // 50001
    int*   cursor   = offsets + N_NODES + 1;        // 50000
    int*   srcbuf   = cursor + N_NODES;             // 800000
    int*   scanp    = srcbuf + N_EDGES;             // 196
    float* spart    = (float*)(scanp + 256);        // 12500*256 floats (12.8 MB)
    float* out      = (float*)d_out;

    hipMemsetAsync(cnt, 0, N_NODES * sizeof(int), stream);
    hipMemsetAsync(stats, 0, 512 * sizeof(float), stream);

    // W split/transpose (once per launch) + CSR build
    wsplit_kernel     <<<128,         256, 0, stream>>>(W1, W2, wt);
    hist_kernel       <<<3125,        256, 0, stream>>>(colp, cnt);
    scan_partials_sum <<<SCAN_BLOCKS, 256, 0, stream>>>(cnt, scanp);
    scan_partials_scan<<<1,           256, 0, stream>>>(scanp, offsets);
    scan_final        <<<SCAN_BLOCKS, 256, 0, stream>>>(cnt, scanp, offsets, cursor);
    bucket_kernel     <<<3125,        256, 0, stream>>>(rowp, colp, cursor, srcbuf);

    // layer 1: sup = x@W1 (split-bf16 MFMA), agg = A·sup + fused stats
    gemm_mfma<false><<<1563,       256, 0, stream>>>(x, wt, nullptr, sup);
    aggregate_bf16  <<<AGG_BLOCKS, 256, 0, stream>>>(sup, offsets, srcbuf, agg, spart);
    stats_reduce    <<<RED_BLOCKS, 256, 0, stream>>>(spart, stats);
    bn_coef_kernel  <<<1,          128, 0, stream>>>(stats, gamma1, beta1, coef);

    // layer 2: sup = relu(bn(agg))@W2 (BN fused into staging), agg = A·sup + stats
    gemm_mfma<true> <<<1563,       256, 0, stream>>>(agg, wt + 32768, coef, sup);
    aggregate_bf16  <<<AGG_BLOCKS, 256, 0, stream>>>(sup, offsets, srcbuf, agg, spart);
    stats_reduce    <<<RED_BLOCKS, 256, 0, stream>>>(spart, stats + 256);
    bn_coef_kernel  <<<1,          128, 0, stream>>>(stats + 256, gamma2, beta2, coef + 256);

    // layer 3: sup3 = relu(bn(agg))@W3 (fused GEMV), out = A·sup3 + b3 (CSR gather)
    gemv_bn_kernel   <<<25000, 256, 0, stream>>>(agg, coef + 256, W3, sup3);
    gather_out_kernel<<<SCAN_BLOCKS, 256, 0, stream>>>(offsets, srcbuf, sup3, b3, out);
}

// Round 8
// 455.141 us; speedup vs baseline: 1.5091x; 1.1367x over previous
//
#include <hip/hip_runtime.h>

#define N_NODES 50000
#define N_EDGES 800000
#define FDIM 128
#define NROWS 100000   // B * N_NODES
#define BN_EPS 1e-5f
#define SCAN_BLOCKS 196   // ceil(50000 / 256)

typedef unsigned short ushort_t;
typedef unsigned int uint_t;
typedef __attribute__((ext_vector_type(8))) short bf16x8;   // MFMA A/B frag
typedef __attribute__((ext_vector_type(4))) float f32x4;    // MFMA C/D frag

// round-to-nearest-even fp32 -> bf16
__device__ inline ushort_t f2bf(float f) {
    uint_t x = __float_as_uint(f);
    x += 0x7fffu + ((x >> 16) & 1u);
    return (ushort_t)(x >> 16);
}
__device__ inline float4 bf4_to_f4(ushort4 u) {
    float4 f;
    f.x = __uint_as_float((uint_t)u.x << 16);
    f.y = __uint_as_float((uint_t)u.y << 16);
    f.z = __uint_as_float((uint_t)u.z << 16);
    f.w = __uint_as_float((uint_t)u.w << 16);
    return f;
}
// split-bf16: f = hi + lo with |err| ~ 2^-18 |f|
__device__ inline void split4(float4 v, bf16x8& hi, bf16x8& lo, int base) {
    float f[4] = {v.x, v.y, v.z, v.w};
    #pragma unroll
    for (int t = 0; t < 4; ++t) {
        ushort_t h = f2bf(f[t]);
        float fh = __uint_as_float((uint_t)h << 16);
        ushort_t l = f2bf(f[t] - fh);
        hi[base + t] = (short)h;
        lo[base + t] = (short)l;
    }
}

// ---------------- CSR build (per-destination buckets) ----------------

__global__ __launch_bounds__(256) void hist_kernel(const int* __restrict__ col,
                                                   int* __restrict__ cnt) {
    int e = blockIdx.x * 256 + threadIdx.x;
    if (e < N_EDGES) atomicAdd(&cnt[col[e]], 1);
}

__global__ __launch_bounds__(256) void scan_partials_sum(const int* __restrict__ cnt,
                                                         int* __restrict__ partials) {
    __shared__ int ws[4];
    int tid = threadIdx.x, lane = tid & 63, wid = tid >> 6;
    int i = blockIdx.x * 256 + tid;
    int v = (i < N_NODES) ? cnt[i] : 0;
    #pragma unroll
    for (int d = 32; d > 0; d >>= 1) v += __shfl_xor(v, d);
    if (lane == 0) ws[wid] = v;
    __syncthreads();
    if (tid == 0) partials[blockIdx.x] = ws[0] + ws[1] + ws[2] + ws[3];
}

__global__ __launch_bounds__(256) void scan_partials_scan(int* __restrict__ partials,
                                                          int* __restrict__ offsets) {
    __shared__ int ws[4];
    int tid = threadIdx.x, lane = tid & 63, wid = tid >> 6;
    int v = (tid < SCAN_BLOCKS) ? partials[tid] : 0;
    int x = v;
    #pragma unroll
    for (int d = 1; d < 64; d <<= 1) {
        int y = __shfl_up(x, d);
        if (lane >= d) x += y;
    }
    if (lane == 63) ws[wid] = x;
    __syncthreads();
    int woff = 0;
    for (int w = 0; w < wid; ++w) woff += ws[w];
    if (tid < SCAN_BLOCKS) partials[tid] = woff + x - v;   // exclusive
    if (tid == 255) offsets[N_NODES] = woff + x;           // grand total
}

__global__ __launch_bounds__(256) void scan_final(const int* __restrict__ cnt,
                                                  const int* __restrict__ partials,
                                                  int* __restrict__ offsets,
                                                  int* __restrict__ cursor) {
    __shared__ int ws[4];
    int tid = threadIdx.x, lane = tid & 63, wid = tid >> 6;
    int i = blockIdx.x * 256 + tid;
    int v = (i < N_NODES) ? cnt[i] : 0;
    int x = v;
    #pragma unroll
    for (int d = 1; d < 64; d <<= 1) {
        int y = __shfl_up(x, d);
        if (lane >= d) x += y;
    }
    if (lane == 63) ws[wid] = x;
    __syncthreads();
    int woff = 0;
    for (int w = 0; w < wid; ++w) woff += ws[w];
    if (i < N_NODES) {
        int off = partials[blockIdx.x] + woff + x - v;
        offsets[i] = off;
        cursor[i] = off;
    }
}

__global__ __launch_bounds__(256) void bucket_kernel(const int* __restrict__ row,
                                                     const int* __restrict__ col,
                                                     int* __restrict__ cursor,
                                                     int* __restrict__ srcbuf) {
    int e = blockIdx.x * 256 + threadIdx.x;
    if (e < N_EDGES) {
        int c = col[e];
        int p = atomicAdd(&cursor[c], 1);
        srcbuf[p] = row[e];
    }
}

// ---------------- W pre-transform + workspace zeroing ----------------
// Also zeroes cnt (needed by hist) and stats (needed by bn_stats) -> drops 2 memsets.
__global__ __launch_bounds__(256) void wsplit_kernel(const float* __restrict__ W1,
                                                     const float* __restrict__ W2,
                                                     ushort_t* __restrict__ wt,
                                                     int* __restrict__ cnt,
                                                     float* __restrict__ stats) {
    int idx = blockIdx.x * 256 + threadIdx.x;   // 0..32767
    for (int i = idx; i < N_NODES; i += 32768) cnt[i] = 0;
    if (idx < 512) stats[idx] = 0.f;
    int which = idx >> 14;
    int e = idx & 16383;                         // e = k*128 + n (coalesced read)
    int k = e >> 7, n = e & 127;
    float f = (which ? W2 : W1)[e];
    ushort_t h = f2bf(f);
    float fh = __uint_as_float((uint_t)h << 16);
    ushort_t l = f2bf(f - fh);
    size_t base = (size_t)which * 32768;
    wt[base + n * 128 + k] = h;                  // hi plane
    wt[base + 16384 + n * 128 + k] = l;          // lo plane
}

// ---------------- GEMM via split-bf16 MFMA (BN coef computed in-block) ----------------
template <bool BN>
__global__ __launch_bounds__(256) void gemm_mfma(const float* __restrict__ A,
                                                 const ushort_t* __restrict__ wt,
                                                 const float* __restrict__ stats,
                                                 const float* __restrict__ gamma,
                                                 const float* __restrict__ beta,
                                                 ushort_t* __restrict__ C) {
    __shared__ short lds[32768];  // Ah[0,8192) Al[8192,16384) Wh[16384,24576) Wl[24576,32768)
    __shared__ float cs[256];     // scale[0:128], shift[128:256]
    int tid = threadIdx.x;
    long r0 = (long)blockIdx.x * 64;
    const float4* A4 = (const float4*)A;

    if (BN) {
        if (tid < 128) {
            float inv = 1.0f / (float)NROWS;
            float mean = stats[tid] * inv;
            float var = stats[128 + tid] * inv - mean * mean;
            float scale = gamma[tid] / sqrtf(var + BN_EPS);
            cs[tid] = scale;
            cs[128 + tid] = beta[tid] - mean * scale;
        }
        __syncthreads();
    }
    const float4* coef4 = (const float4*)cs;

    #pragma unroll
    for (int i = 0; i < 4; ++i) {
        int li = tid + i * 256;
        int r = li >> 4, j = li & 15;        // row 0..63, k-block 0..15
        long gr = r0 + r;
        float4 va = make_float4(0.f, 0.f, 0.f, 0.f), vb = va;
        if (gr < NROWS) { va = A4[gr * 32 + j * 2]; vb = A4[gr * 32 + j * 2 + 1]; }
        if (BN) {
            float4 sc = coef4[j * 2], sh = coef4[32 + j * 2];
            va.x = fmaxf(va.x * sc.x + sh.x, 0.f);
            va.y = fmaxf(va.y * sc.y + sh.y, 0.f);
            va.z = fmaxf(va.z * sc.z + sh.z, 0.f);
            va.w = fmaxf(va.w * sc.w + sh.w, 0.f);
            sc = coef4[j * 2 + 1]; sh = coef4[32 + j * 2 + 1];
            vb.x = fmaxf(vb.x * sc.x + sh.x, 0.f);
            vb.y = fmaxf(vb.y * sc.y + sh.y, 0.f);
            vb.z = fmaxf(vb.z * sc.z + sh.z, 0.f);
            vb.w = fmaxf(vb.w * sc.w + sh.w, 0.f);
        }
        bf16x8 vh, vl;
        split4(va, vh, vl, 0);
        split4(vb, vh, vl, 4);
        int off = r * 128 + ((j ^ (r & 15)) * 8);
        *(bf16x8*)&lds[off] = vh;
        *(bf16x8*)&lds[8192 + off] = vl;
    }

    int w = tid >> 6, l = tid & 63;
    int m = l & 15, q = l >> 4;
    for (int half = 0; half < 2; ++half) {
        __syncthreads();
        #pragma unroll
        for (int i = 0; i < 8; ++i) {
            int li = tid + i * 256;
            int p = li >> 10;                 // 0=hi 1=lo
            int rest = li & 1023;
            int nl = rest >> 4, j = rest & 15;
            bf16x8 v = *(const bf16x8*)&wt[(size_t)p * 16384 + (half * 64 + nl) * 128 + j * 8];
            *(bf16x8*)&lds[16384 + p * 8192 + nl * 128 + ((j ^ (nl & 15)) * 8)] = v;
        }
        __syncthreads();

        f32x4 acc[4] = {};
        #pragma unroll
        for (int s = 0; s < 4; ++s) {
            int x = (s * 4 + q) ^ m;
            int aoff = (w * 16 + m) * 128 + x * 8;
            bf16x8 ah = *(const bf16x8*)&lds[aoff];
            bf16x8 al = *(const bf16x8*)&lds[8192 + aoff];
            #pragma unroll
            for (int c = 0; c < 4; ++c) {
                int boff = 16384 + (c * 16 + m) * 128 + x * 8;
                bf16x8 bh = *(const bf16x8*)&lds[boff];
                bf16x8 bl = *(const bf16x8*)&lds[8192 + boff];
                acc[c] = __builtin_amdgcn_mfma_f32_16x16x32_bf16(al, bh, acc[c], 0, 0, 0);
                acc[c] = __builtin_amdgcn_mfma_f32_16x16x32_bf16(ah, bl, acc[c], 0, 0, 0);
                acc[c] = __builtin_amdgcn_mfma_f32_16x16x32_bf16(ah, bh, acc[c], 0, 0, 0);
            }
        }

        #pragma unroll
        for (int c = 0; c < 4; ++c) {
            #pragma unroll
            for (int r = 0; r < 4; ++r) {
                long gr = r0 + w * 16 + q * 4 + r;
                if (gr < NROWS)
                    C[gr * 128 + half * 64 + c * 16 + m] = f2bf(acc[c][r]);
            }
        }
    }
}

// ---------------- Aggregate (round-5 verified hot loop, no stats fusion) ----------------
__global__ __launch_bounds__(256) void aggregate_bf16(const ushort_t* __restrict__ sup,
                                                      const int* __restrict__ offsets,
                                                      const int* __restrict__ srcbuf,
                                                      float* __restrict__ agg) {
    int lane = threadIdx.x & 63;
    int wid = threadIdx.x >> 6;
    int node = blockIdx.x * 4 + wid;        // 12500*4 = 50000 exactly
    int s = lane >> 5;       // half-wave id
    int l32 = lane & 31;
    int beg = offsets[node], end = offsets[node + 1];
    const ushort4* sb0 = (const ushort4*)sup;                               // batch 0
    const ushort4* sb1 = (const ushort4*)(sup + (size_t)N_NODES * FDIM);    // batch 1
    float4 a0 = make_float4(0.f, 0.f, 0.f, 0.f);
    float4 a1 = make_float4(0.f, 0.f, 0.f, 0.f);
    for (int i = beg; i < end; i += 64) {
        int m = end - i; if (m > 64) m = 64;
        int idx = (i + lane < end) ? srcbuf[i + lane] : 0;  // coalesced index load
        int tmax = (m + 1) >> 1;
        #pragma unroll 2
        for (int t = 0; t < tmax; ++t) {
            int j = 2 * t + s;
            int r = __shfl(idx, j & 63);
            ushort4 u0 = sb0[(size_t)r * 32 + l32];
            ushort4 u1 = sb1[(size_t)r * 32 + l32];
            if (j < m) {
                float4 f0 = bf4_to_f4(u0);
                float4 f1 = bf4_to_f4(u1);
                a0.x += f0.x; a0.y += f0.y; a0.z += f0.z; a0.w += f0.w;
                a1.x += f1.x; a1.y += f1.y; a1.z += f1.z; a1.w += f1.w;
            }
        }
    }
    a0.x += __shfl_xor(a0.x, 32); a0.y += __shfl_xor(a0.y, 32);
    a0.z += __shfl_xor(a0.z, 32); a0.w += __shfl_xor(a0.w, 32);
    a1.x += __shfl_xor(a1.x, 32); a1.y += __shfl_xor(a1.y, 32);
    a1.z += __shfl_xor(a1.z, 32); a1.w += __shfl_xor(a1.w, 32);
    float4* ag = (float4*)agg;
    if (s == 0) ag[(size_t)node * 32 + l32] = a0;                       // batch 0 row
    else        ag[(size_t)(N_NODES + node) * 32 + l32] = a1;           // batch 1 row
}

// ---------------- BatchNorm stats (over raw agg) ----------------

__global__ __launch_bounds__(256) void bn_stats_kernel(const float* __restrict__ h,
                                                       float* __restrict__ stats) {
    __shared__ float ls[256], ls2[256];
    int tid = threadIdx.x;
    int f = tid & 127, half = tid >> 7;
    float s = 0.f, s2 = 0.f;
    for (int row = blockIdx.x * 2 + half; row < NROWS; row += gridDim.x * 2) {
        float v = h[(size_t)row * FDIM + f];
        s += v; s2 += v * v;
    }
    ls[tid] = s; ls2[tid] = s2;
    __syncthreads();
    if (tid < 128) {
        atomicAdd(&stats[f], ls[tid] + ls[tid + 128]);
        atomicAdd(&stats[128 + f], ls2[tid] + ls2[tid + 128]);
    }
}

// ---------------- Layer 3: fused BN+ReLU GEMV (coef in-block) + CSR gather ----------------
// grid 6250, each wave handles 4 rows -> coef compute amortized.
__global__ __launch_bounds__(256) void gemv_bn_kernel(const float* __restrict__ h,
                                                      const float* __restrict__ stats,
                                                      const float* __restrict__ gamma,
                                                      const float* __restrict__ beta,
                                                      const float* __restrict__ W3,
                                                      float* __restrict__ sup3) {
    __shared__ float cs[256];
    int tid = threadIdx.x;
    if (tid < 128) {
        float inv = 1.0f / (float)NROWS;
        float mean = stats[tid] * inv;
        float var = stats[128 + tid] * inv - mean * mean;
        float scale = gamma[tid] / sqrtf(var + BN_EPS);
        cs[tid] = scale;
        cs[128 + tid] = beta[tid] - mean * scale;
    }
    __syncthreads();
    int lane = tid & 63, wid = tid >> 6;
    float2 w  = ((const float2*)W3)[lane];
    float2 sc = ((const float2*)cs)[lane];
    float2 sh = ((const float2*)(cs + 128))[lane];
    #pragma unroll
    for (int r = 0; r < 4; ++r) {
        long gw = (long)blockIdx.x * 16 + wid * 4 + r;   // 6250*16 = 100000 exactly
        float2 v = ((const float2*)h)[(size_t)gw * 64 + lane];
        v.x = fmaxf(v.x * sc.x + sh.x, 0.f);
        v.y = fmaxf(v.y * sc.y + sh.y, 0.f);
        float s = v.x * w.x + v.y * w.y;
        #pragma unroll
        for (int d = 32; d > 0; d >>= 1) s += __shfl_xor(s, d);
        if (lane == 0) sup3[gw] = s;
    }
}

// out[b,n] = b3 + sum over CSR in-edges of sup3[b, src].
__global__ __launch_bounds__(256) void gather_out_kernel(const int* __restrict__ offsets,
                                                         const int* __restrict__ srcbuf,
                                                         const float* __restrict__ sup3,
                                                         const float* __restrict__ b3,
                                                         float* __restrict__ out) {
    int n = blockIdx.x * 256 + threadIdx.x;
    if (n >= N_NODES) return;
    int beg = offsets[n], end = offsets[n + 1];
    float s0 = 0.f, s1 = 0.f;
    for (int i = beg; i < end; ++i) {
        int r = srcbuf[i];
        s0 += sup3[r];
        s1 += sup3[N_NODES + r];
    }
    float b = b3[0];
    out[n] = s0 + b;
    out[N_NODES + n] = s1 + b;
}

// ---------------- launch ----------------

extern "C" void kernel_launch(void* const* d_in, const int* in_sizes, int n_in,
                              void* d_out, int out_size, void* d_ws, size_t ws_size,
                              hipStream_t stream) {
    const float* x      = (const float*)d_in[0];
    const int*   ei     = (const int*)d_in[1];
    const float* W1     = (const float*)d_in[2];
    // d_in[3] = b1: per-feature bias before BN cancels exactly (shifts mean identically)
    const float* W2     = (const float*)d_in[4];
    // d_in[5] = b2: same cancellation
    const float* W3     = (const float*)d_in[6];
    const float* b3     = (const float*)d_in[7];
    const float* gamma1 = (const float*)d_in[8];
    const float* beta1  = (const float*)d_in[9];
    const float* gamma2 = (const float*)d_in[10];
    const float* beta2  = (const float*)d_in[11];
    const int* rowp = ei;             // edge_index[0]
    const int* colp = ei + N_EDGES;   // edge_index[1]

    ushort_t* sup   = (ushort_t*)d_ws;              // 12.8M bf16 (25.6 MB)
    float* agg      = (float*)(sup + 12800000);     // 12.8M floats (51.2 MB)
    float* sup3     = agg + 12800000;               // 100k floats
    ushort_t* wt    = (ushort_t*)(sup3 + 100000);   // 65536 ushorts: W1/W2 split planes
    float* stats    = (float*)(wt + 65536);         // 512 floats
    int*   cnt      = (int*)(stats + 512);          // 50000
    int*   offsets  = cnt + N_NODES;                // 50001
    int*   cursor   = offsets + N_NODES + 1;        // 50000
    int*   srcbuf   = cursor + N_NODES;             // 800000
    int*   scanp    = srcbuf + N_EDGES;             // 196
    float* out      = (float*)d_out;

    // W split/transpose + cnt/stats zeroing, then CSR build
    wsplit_kernel     <<<128,         256, 0, stream>>>(W1, W2, wt, cnt, stats);
    hist_kernel       <<<3125,        256, 0, stream>>>(colp, cnt);
    scan_partials_sum <<<SCAN_BLOCKS, 256, 0, stream>>>(cnt, scanp);
    scan_partials_scan<<<1,           256, 0, stream>>>(scanp, offsets);
    scan_final        <<<SCAN_BLOCKS, 256, 0, stream>>>(cnt, scanp, offsets, cursor);
    bucket_kernel     <<<3125,        256, 0, stream>>>(rowp, colp, cursor, srcbuf);

    // layer 1: sup = x@W1 (split-bf16 MFMA), agg = A·sup, stats
    gemm_mfma<false><<<1563,  256, 0, stream>>>(x, wt, nullptr, nullptr, nullptr, sup);
    aggregate_bf16  <<<12500, 256, 0, stream>>>(sup, offsets, srcbuf, agg);
    bn_stats_kernel <<<512,   256, 0, stream>>>(agg, stats);

    // layer 2: sup = relu(bn1(agg))@W2 (coef computed in-block), agg = A·sup, stats
    gemm_mfma<true> <<<1563,  256, 0, stream>>>(agg, wt + 32768, stats, gamma1, beta1, sup);
    aggregate_bf16  <<<12500, 256, 0, stream>>>(sup, offsets, srcbuf, agg);
    bn_stats_kernel <<<512,   256, 0, stream>>>(agg, stats + 256);

    // layer 3: sup3 = relu(bn2(agg))@W3 (coef in-block), out = A·sup3 + b3 (CSR gather)
    gemv_bn_kernel   <<<6250, 256, 0, stream>>>(agg, stats + 256, gamma2, beta2, W3, sup3);
    gather_out_kernel<<<SCAN_BLOCKS, 256, 0, stream>>>(offsets, srcbuf, sup3, b3, out);
}